// Round 1
// baseline (47.316 us; speedup 1.0000x reference)
//
#include <hip/hip_runtime.h>

// FSUSqrt: T=64 sequential steps of a per-element stochastic-computing sqrt
// unit over N=524288 independent bit-stream columns.
// Per column state: acc (accumulator), emit (feedback bit), sr0 (shift-reg
// head; sr[1] is never read -> dead state).
// Step: acc = clip(acc + x + emit, -256, 256); out = acc >= 1;
//       acc -= out; emit = sr0_old * out; sr0 = 1 - out.
// Memory-bound: ~264 MiB total traffic -> ~42 us roofline at 6.3 TB/s.

constexpr int T = 64;
constexpr int N = 524288;
constexpr int NV = N / 4;          // float4 groups per time step
constexpr int BLOCK = 256;

__device__ __forceinline__ float stepf(float x, float& acc, float& emit, float& sr0) {
    float a = acc + x + emit;
    a = fminf(fmaxf(a, -256.0f), 256.0f);   // clamp (never triggers, but free)
    float o = (a >= 1.0f) ? 1.0f : 0.0f;
    acc = a - o;
    float e = sr0 * o;                       // scrambled (old sr[0]) AND out
    sr0 = 1.0f - o;                          // new sr[0] = 1 - out
    emit = e;
    return o;
}

__global__ __launch_bounds__(BLOCK) void fsusqrt_kernel(
    const float4* __restrict__ x,          // [T][NV]
    const float4* __restrict__ emit_init,  // [NV]
    const float4* __restrict__ acc_init,   // [NV]
    const float4* __restrict__ sr_init,    // [2][NV], row 0 used
    float4* __restrict__ out)              // [T][NV]
{
    const int i = blockIdx.x * BLOCK + threadIdx.x;
    if (i >= NV) return;

    float4 emit = emit_init[i];
    float4 acc  = acc_init[i];
    float4 sr0  = sr_init[i];              // row 0 only; row 1 is dead state

    // 2-deep software prefetch: always keep >=1 HBM load in flight.
    float4 buf0 = x[i];
    float4 buf1 = x[NV + i];

    #pragma unroll
    for (int t = 0; t < T; ++t) {
        float4 cur = buf0;
        buf0 = buf1;
        if (t + 2 < T) buf1 = x[(t + 2) * NV + i];

        float4 o;
        o.x = stepf(cur.x, acc.x, emit.x, sr0.x);
        o.y = stepf(cur.y, acc.y, emit.y, sr0.y);
        o.z = stepf(cur.z, acc.z, emit.z, sr0.z);
        o.w = stepf(cur.w, acc.w, emit.w, sr0.w);

        out[t * NV + i] = o;
    }
}

extern "C" void kernel_launch(void* const* d_in, const int* in_sizes, int n_in,
                              void* d_out, int out_size, void* d_ws, size_t ws_size,
                              hipStream_t stream) {
    const float4* x         = (const float4*)d_in[0];   // [T][N] bits as f32
    const float4* emit_init = (const float4*)d_in[1];   // [N]
    const float4* acc_init  = (const float4*)d_in[2];   // [N]
    const float4* sr_init   = (const float4*)d_in[3];   // [2][N]
    float4* out = (float4*)d_out;                       // [T][N]

    dim3 grid(NV / BLOCK);   // 512 blocks
    dim3 block(BLOCK);
    fsusqrt_kernel<<<grid, block, 0, stream>>>(x, emit_init, acc_init, sr_init, out);
}